// Round 1
// 827.484 us; speedup vs baseline: 1.1021x; 1.1021x over previous
//
#include <hip/hip_runtime.h>

// SelfAttentionBlock channel-attention, MI355X fp16-MFMA pipeline.
// N=32, C=512, A=256, H=W=64 (P=4096 flat spatial, PP=1024 pooled).

typedef _Float16 half8 __attribute__((ext_vector_type(8)));
typedef _Float16 half4v __attribute__((ext_vector_type(4)));
typedef float f32x4 __attribute__((ext_vector_type(4)));

#define NB 32
#define CD 512
#define AD 256
#define PD 4096
#define PPD 1024

// ---------------- workspace layout (bytes) ----------------
// xT   : fp16 (N, P, C)   = 134217728    k=c contiguous (GEMM1 B-operand)
// Wc   : fp16 (512, 512)  = 524288       rows 0-255 = w_g, 256-511 = w_phi
// theta: fp16 (N, C, PP)  = 33554432     pooled x, k=m' contiguous
// gT   : fp16 (N, P, A)   = 67108864     g_x transposed, k=a contiguous
// phi  : fp16 (N, A, PP)  = 16777216     pooled phi-conv
// attn : fp16 (N, C, A)   = 8388608
// total = 260571136 B (fits under 268435456 = out bytes)
#define OFF_XT    0UL
#define OFF_WC    134217728UL
#define OFF_THETA 134742016UL
#define OFF_GT    168296448UL
#define OFF_PHI   235405312UL
#define OFF_ATTN  252182528UL

__global__ __launch_bounds__(256) void k_prep_w(const float* __restrict__ w_g,
                                                const float* __restrict__ w_phi,
                                                _Float16* __restrict__ Wc) {
    int idx4 = blockIdx.x * 256 + threadIdx.x;   // 65536 float4 chunks
    int flat = idx4 * 4;
    const float* src = (flat < AD * CD) ? (w_g + flat) : (w_phi + (flat - AD * CD));
    float4 v = *(const float4*)src;
    half4v h;
    h[0] = (_Float16)v.x; h[1] = (_Float16)v.y; h[2] = (_Float16)v.z; h[3] = (_Float16)v.w;
    *(half4v*)(Wc + flat) = h;
}

// Read x fp32 tile (32 c x 128 p), produce xT fp16 (transposed) + theta (pooled).
__global__ __launch_bounds__(256) void k_prep_x(const float* __restrict__ x,
                                                _Float16* __restrict__ xT,
                                                _Float16* __restrict__ theta) {
    __shared__ _Float16 tile[32 * 136];   // [c][p], stride 136 halves
    int pb = blockIdx.x;   // 0..31  -> p0 = pb*128 (two image rows h=2pb,2pb+1)
    int cb = blockIdx.y;   // 0..15  -> c0 = cb*32
    int n  = blockIdx.z;
    int t  = threadIdx.x;
    int p0 = pb * 128, c0 = cb * 32;

    const float* xbase = x + ((size_t)n * CD + c0) * PD + p0;
#pragma unroll
    for (int i = 0; i < 4; ++i) {
        int idx = i * 256 + t;        // 1024 float4 chunks
        int cl = idx >> 5;            // 0..31
        int ch = idx & 31;            // p offset = ch*4
        float4 v = *(const float4*)(xbase + (size_t)cl * PD + ch * 4);
        half4v h;
        h[0] = (_Float16)v.x; h[1] = (_Float16)v.y; h[2] = (_Float16)v.z; h[3] = (_Float16)v.w;
        *(half4v*)&tile[cl * 136 + ch * 4] = h;
    }
    __syncthreads();

    // xT write: thread t -> p-row pl = t>>1, c-chunk (t&1)*16
    {
        int pl = t >> 1, ch = t & 1;
        _Float16 vals[16] __attribute__((aligned(16)));
#pragma unroll
        for (int j = 0; j < 16; ++j) vals[j] = tile[(ch * 16 + j) * 136 + pl];
        _Float16* dst = xT + ((size_t)n * PD + p0 + pl) * CD + c0 + ch * 16;
        *(uint4*)dst       = *(uint4*)&vals[0];
        *(uint4*)(dst + 8) = *(uint4*)&vals[8];
    }
    // theta (2x2 maxpool): thread t -> c-row cl = t>>3, 4 outputs at u0=(t&7)*4
    {
        int cl = t >> 3, u0 = (t & 7) * 4;
        _Float16 o[4] __attribute__((aligned(8)));
#pragma unroll
        for (int j = 0; j < 4; ++j) {
            int w2 = (u0 + j) * 2;
            float a0 = (float)tile[cl * 136 + w2];
            float a1 = (float)tile[cl * 136 + w2 + 1];
            float a2 = (float)tile[cl * 136 + 64 + w2];
            float a3 = (float)tile[cl * 136 + 64 + w2 + 1];
            o[j] = (_Float16)fmaxf(fmaxf(a0, a1), fmaxf(a2, a3));
        }
        _Float16* dst = theta + ((size_t)n * CD + c0 + cl) * PPD + pb * 32 + u0;
        *(uint2*)dst = *(uint2*)&o[0];
    }
}

// GEMM1: D[a][p] = sum_c Wc[a][c] * x[c][p]  (per batch n), 128x128 tile, K=512.
// a0<256: +b_g, write gT[n][p][a] (LDS transpose).  a0>=256: +b_phi, 2x2 pool, write phi[n][a][m'].
__global__ __launch_bounds__(256) void k_gemm1(const _Float16* __restrict__ Wc,
                                               const _Float16* __restrict__ xT,
                                               const float* __restrict__ b_g,
                                               const float* __restrict__ b_phi,
                                               _Float16* __restrict__ gT,
                                               _Float16* __restrict__ phi) {
    __shared__ _Float16 smem[17408];      // staging: A[128][40] + B[128][40]; epilogue: [128][136]
    _Float16* As = smem;
    _Float16* Bs = smem + 5120;

    int pb = blockIdx.x, ab = blockIdx.y, n = blockIdx.z;
    int a0 = ab * 128, p0 = pb * 128;
    int t = threadIdx.x;
    int w = t >> 6, l = t & 63;
    int ln = l & 15, q = l >> 4;
    int mw = (w >> 1) * 64, nw = (w & 1) * 64;

    const f32x4 vzero = {0.f, 0.f, 0.f, 0.f};
    f32x4 acc[4][4];
#pragma unroll
    for (int i = 0; i < 4; ++i)
#pragma unroll
        for (int j = 0; j < 4; ++j) acc[i][j] = vzero;

    const _Float16* Abase = Wc + (size_t)a0 * CD;
    const _Float16* Bbase = xT + ((size_t)n * PD + p0) * CD;

    for (int k0 = 0; k0 < 512; k0 += 32) {
#pragma unroll
        for (int i = 0; i < 2; ++i) {
            int idx = i * 256 + t;
            int row = idx >> 2, ch = idx & 3;
            *(half8*)&As[row * 40 + ch * 8] = *(const half8*)(Abase + (size_t)row * CD + k0 + ch * 8);
            *(half8*)&Bs[row * 40 + ch * 8] = *(const half8*)(Bbase + (size_t)row * CD + k0 + ch * 8);
        }
        __syncthreads();
        half8 af[4], bf[4];
#pragma unroll
        for (int mt = 0; mt < 4; ++mt) af[mt] = *(const half8*)&As[(mw + mt * 16 + ln) * 40 + q * 8];
#pragma unroll
        for (int nt = 0; nt < 4; ++nt) bf[nt] = *(const half8*)&Bs[(nw + nt * 16 + ln) * 40 + q * 8];
#pragma unroll
        for (int mt = 0; mt < 4; ++mt)
#pragma unroll
            for (int nt = 0; nt < 4; ++nt)
                acc[mt][nt] = __builtin_amdgcn_mfma_f32_16x16x32_f16(af[mt], bf[nt], acc[mt][nt], 0, 0, 0);
        __syncthreads();
    }

    bool is_g = (a0 < 256);
    const float* bias = is_g ? b_g : b_phi;
    int abase = a0 - (is_g ? 0 : 256);
    float bv[4][4];
#pragma unroll
    for (int mt = 0; mt < 4; ++mt)
#pragma unroll
        for (int r = 0; r < 4; ++r) bv[mt][r] = bias[abase + mw + mt * 16 + q * 4 + r];

    _Float16* T = smem;   // [row][136]
    if (is_g) {
        // transpose into [p_local][a_local]
#pragma unroll
        for (int mt = 0; mt < 4; ++mt)
#pragma unroll
            for (int nt = 0; nt < 4; ++nt)
#pragma unroll
                for (int r = 0; r < 4; ++r) {
                    int al = mw + mt * 16 + q * 4 + r;
                    int pl = nw + nt * 16 + ln;
                    T[pl * 136 + al] = (_Float16)(acc[mt][nt][r] + bv[mt][r]);
                }
        __syncthreads();
#pragma unroll
        for (int i = 0; i < 8; ++i) {
            int idx = i * 256 + t;
            int pl = idx >> 4, ch = idx & 15;
            uint4 v = *(uint4*)&T[pl * 136 + ch * 8];
            *(uint4*)(gT + ((size_t)n * PD + p0 + pl) * AD + a0 + ch * 8) = v;
        }
    } else {
        // [a_local][p_local] then 2x2 pool (cols 0..63 = row h0, 64..127 = row h0+1)
#pragma unroll
        for (int mt = 0; mt < 4; ++mt)
#pragma unroll
            for (int nt = 0; nt < 4; ++nt)
#pragma unroll
                for (int r = 0; r < 4; ++r) {
                    int al = mw + mt * 16 + q * 4 + r;
                    int pl = nw + nt * 16 + ln;
                    T[al * 136 + pl] = (_Float16)(acc[mt][nt][r] + bv[mt][r]);
                }
        __syncthreads();
        int al = t >> 1, hf = t & 1;
        _Float16 o[16] __attribute__((aligned(16)));
#pragma unroll
        for (int j = 0; j < 16; ++j) {
            int u = hf * 16 + j;
            float v0 = (float)T[al * 136 + 2 * u];
            float v1 = (float)T[al * 136 + 2 * u + 1];
            float v2 = (float)T[al * 136 + 64 + 2 * u];
            float v3 = (float)T[al * 136 + 64 + 2 * u + 1];
            o[j] = (_Float16)fmaxf(fmaxf(v0, v1), fmaxf(v2, v3));
        }
        _Float16* dst = phi + ((size_t)n * AD + (a0 - 256) + al) * PPD + pb * 32 + hf * 16;
        *(uint4*)dst       = *(uint4*)&o[0];
        *(uint4*)(dst + 8) = *(uint4*)&o[8];
    }
}

// GEMM2 + softmax: cmat[c][a] = sum_m theta[c][m] phi[a][m]; attn = softmax_a.
// Block = (n, 64 c-rows); each wave: 16 c x 256 a, K=1024, direct global->frag loads.
__global__ __launch_bounds__(256) void k_gemm2(const _Float16* __restrict__ theta,
                                               const _Float16* __restrict__ phi,
                                               _Float16* __restrict__ attn) {
    int cb = blockIdx.x;   // 0..7
    int n  = blockIdx.y;
    int t = threadIdx.x, w = t >> 6, l = t & 63;
    int ln = l & 15, q = l >> 4;
    int c0 = cb * 64 + w * 16;

    const _Float16* Ab = theta + ((size_t)n * CD + c0 + ln) * PPD;
    const _Float16* Bb = phi + ((size_t)n * AD + ln) * PPD;

    const f32x4 vzero = {0.f, 0.f, 0.f, 0.f};
    f32x4 acc[16];
#pragma unroll
    for (int i = 0; i < 16; ++i) acc[i] = vzero;

    for (int k0 = 0; k0 < 1024; k0 += 32) {
        half8 af = *(const half8*)(Ab + k0 + q * 8);
#pragma unroll
        for (int nt = 0; nt < 16; ++nt) {
            half8 bf = *(const half8*)(Bb + (size_t)nt * 16 * PPD + k0 + q * 8);
            acc[nt] = __builtin_amdgcn_mfma_f32_16x16x32_f16(af, bf, acc[nt], 0, 0, 0);
        }
    }

    // softmax per D-row (row = q*4 + r, cols spread over 16 lanes of the quad x 16 tiles)
#pragma unroll
    for (int r = 0; r < 4; ++r) {
        float m = -1e30f;
#pragma unroll
        for (int nt = 0; nt < 16; ++nt) m = fmaxf(m, acc[nt][r]);
#pragma unroll
        for (int s = 1; s < 16; s <<= 1) m = fmaxf(m, __shfl_xor(m, s, 64));
        float sum = 0.f;
#pragma unroll
        for (int nt = 0; nt < 16; ++nt) {
            float e = __expf(acc[nt][r] - m);
            acc[nt][r] = e;
            sum += e;
        }
#pragma unroll
        for (int s = 1; s < 16; s <<= 1) sum += __shfl_xor(sum, s, 64);
        float inv = 1.0f / sum;
        int c = c0 + q * 4 + r;
        _Float16* dst = attn + ((size_t)n * CD + c) * AD + ln;
#pragma unroll
        for (int nt = 0; nt < 16; ++nt) dst[nt * 16] = (_Float16)(acc[nt][r] * inv);
    }
}

// GEMM3: out[c][p] = sum_a attn[c][a] * gT[p][a] + x[c][p].  128x128 tile, K=256.
// Operand-swapped: D[p][c] so each lane's 4 acc regs = 4 consecutive p -> float4 epilogue.
__global__ __launch_bounds__(256) void k_gemm3(const _Float16* __restrict__ attn,
                                               const _Float16* __restrict__ gT,
                                               const float* __restrict__ x,
                                               float* __restrict__ out) {
    __shared__ _Float16 smem[10240];
    _Float16* As = smem;          // attn tile [128 c][40]
    _Float16* Bs = smem + 5120;   // gT tile   [128 p][40]

    int pb = blockIdx.x, cb = blockIdx.y, n = blockIdx.z;
    int c0 = cb * 128, p0 = pb * 128;
    int t = threadIdx.x;
    int w = t >> 6, l = t & 63;
    int ln = l & 15, q = l >> 4;
    int mw = (w >> 1) * 64, nw = (w & 1) * 64;   // mw: p-tile, nw: c-tile

    const f32x4 vzero = {0.f, 0.f, 0.f, 0.f};
    f32x4 acc[4][4];
#pragma unroll
    for (int i = 0; i < 4; ++i)
#pragma unroll
        for (int j = 0; j < 4; ++j) acc[i][j] = vzero;

    const _Float16* Abase = attn + ((size_t)n * CD + c0) * AD;
    const _Float16* Bbase = gT + ((size_t)n * PD + p0) * AD;

    for (int k0 = 0; k0 < 256; k0 += 32) {
#pragma unroll
        for (int i = 0; i < 2; ++i) {
            int idx = i * 256 + t;
            int row = idx >> 2, ch = idx & 3;
            *(half8*)&As[row * 40 + ch * 8] = *(const half8*)(Abase + (size_t)row * AD + k0 + ch * 8);
            *(half8*)&Bs[row * 40 + ch * 8] = *(const half8*)(Bbase + (size_t)row * AD + k0 + ch * 8);
        }
        __syncthreads();
        half8 af[4], bf[4];
        // A-operand = gT rows (p dim) -> D rows = p; B-operand = attn rows (c dim) -> D cols = c
#pragma unroll
        for (int mt = 0; mt < 4; ++mt) af[mt] = *(const half8*)&Bs[(mw + mt * 16 + ln) * 40 + q * 8];
#pragma unroll
        for (int nt = 0; nt < 4; ++nt) bf[nt] = *(const half8*)&As[(nw + nt * 16 + ln) * 40 + q * 8];
#pragma unroll
        for (int mt = 0; mt < 4; ++mt)
#pragma unroll
            for (int nt = 0; nt < 4; ++nt)
                acc[mt][nt] = __builtin_amdgcn_mfma_f32_16x16x32_f16(af[mt], bf[nt], acc[mt][nt], 0, 0, 0);
        __syncthreads();
    }

    // epilogue: D[p][c]; lane (q,ln) of tile (mt,nt) holds p = p0+mw+mt*16+q*4 .. +3 (contig),
    // c = c0+nw+nt*16+ln.  float4 residual add + store, fully coalesced.
#pragma unroll
    for (int mt = 0; mt < 4; ++mt) {
        int p = p0 + mw + mt * 16 + q * 4;
#pragma unroll
        for (int nt = 0; nt < 4; ++nt) {
            int c = c0 + nw + nt * 16 + ln;
            size_t off = ((size_t)n * CD + c) * PD + p;
            f32x4 xv = *(const f32x4*)(x + off);
            *(f32x4*)(out + off) = acc[mt][nt] + xv;
        }
    }
}

extern "C" void kernel_launch(void* const* d_in, const int* in_sizes, int n_in,
                              void* d_out, int out_size, void* d_ws, size_t ws_size,
                              hipStream_t stream) {
    const float* x     = (const float*)d_in[0];
    const float* w_g   = (const float*)d_in[1];
    const float* b_g   = (const float*)d_in[2];
    const float* w_phi = (const float*)d_in[3];
    const float* b_phi = (const float*)d_in[4];
    float* out = (float*)d_out;

    char* ws = (char*)d_ws;
    _Float16* xT    = (_Float16*)(ws + OFF_XT);
    _Float16* Wc    = (_Float16*)(ws + OFF_WC);
    _Float16* theta = (_Float16*)(ws + OFF_THETA);
    _Float16* gT    = (_Float16*)(ws + OFF_GT);
    _Float16* phi   = (_Float16*)(ws + OFF_PHI);
    _Float16* attn  = (_Float16*)(ws + OFF_ATTN);

    k_prep_w<<<dim3(256), 256, 0, stream>>>(w_g, w_phi, Wc);
    k_prep_x<<<dim3(32, 16, 32), 256, 0, stream>>>(x, xT, theta);
    k_gemm1<<<dim3(32, 4, 32), 256, 0, stream>>>(Wc, xT, b_g, b_phi, gT, phi);
    k_gemm2<<<dim3(8, 32), 256, 0, stream>>>(theta, phi, attn);
    k_gemm3<<<dim3(32, 4, 32), 256, 0, stream>>>(attn, gT, x, out);
}

// Round 2
// 778.572 us; speedup vs baseline: 1.1714x; 1.0628x over previous
//
#include <hip/hip_runtime.h>

// SelfAttentionBlock channel-attention, MI355X fp16-MFMA pipeline.
// N=32, C=512, A=256, H=W=64 (P=4096 flat spatial, PP=1024 pooled).

typedef _Float16 half8 __attribute__((ext_vector_type(8)));
typedef _Float16 half4v __attribute__((ext_vector_type(4)));
typedef float f32x4 __attribute__((ext_vector_type(4)));

#define NB 32
#define CD 512
#define AD 256
#define PD 4096
#define PPD 1024

// ---------------- workspace layout (bytes) ----------------
#define OFF_XT    0UL
#define OFF_WC    134217728UL
#define OFF_THETA 134742016UL
#define OFF_GT    168296448UL
#define OFF_PHI   235405312UL
#define OFF_ATTN  252182528UL

// global->LDS direct (16B/lane). dest must be linear in lane (wave-uniform base + lane*16).
#define GLOAD16(gp, lp) \
    __builtin_amdgcn_global_load_lds((const __attribute__((address_space(1))) void*)(gp), \
                                     (__attribute__((address_space(3))) void*)(lp), 16, 0, 0)

// XOR-swizzled LDS tile [128 rows][32 halves], chunk = 16B (8 halves), 4 chunks/row.
// physical chunk chP at row holds logical chunk chP ^ ((row>>1)&3)  (involution).
__device__ __forceinline__ int swz_off(int row, int q) {
    return row * 32 + ((q ^ ((row >> 1) & 3)) * 8);
}

// Stage one 128x32 A-tile + 128x32 B-tile into LDS via global_load_lds,
// with source pre-swizzled so LDS dest stays linear. LD = row stride (halves).
template <int LD>
__device__ __forceinline__ void stage2(const _Float16* __restrict__ Ab,
                                       const _Float16* __restrict__ Bb,
                                       int k0, _Float16* bufA, _Float16* bufB, int t) {
#pragma unroll
    for (int j = 0; j < 4; ++j) {
        int idx = j * 256 + t;            // 0..1023 chunks (512 A + 512 B)
        int ci = idx & 511;
        int row = ci >> 2, chP = ci & 3;
        int chL = chP ^ ((row >> 1) & 3);
        const _Float16* src = ((idx < 512) ? Ab : Bb) + (size_t)row * LD + k0 + chL * 8;
        _Float16* dst = ((idx < 512) ? bufA : bufB) + ci * 8;
        GLOAD16(src, dst);
    }
}

__global__ __launch_bounds__(256) void k_prep_w(const float* __restrict__ w_g,
                                                const float* __restrict__ w_phi,
                                                _Float16* __restrict__ Wc) {
    int idx4 = blockIdx.x * 256 + threadIdx.x;
    int flat = idx4 * 4;
    const float* src = (flat < AD * CD) ? (w_g + flat) : (w_phi + (flat - AD * CD));
    float4 v = *(const float4*)src;
    half4v h;
    h[0] = (_Float16)v.x; h[1] = (_Float16)v.y; h[2] = (_Float16)v.z; h[3] = (_Float16)v.w;
    *(half4v*)(Wc + flat) = h;
}

// Read x fp32 tile (32 c x 128 p), produce xT fp16 (transposed) + theta (pooled).
__global__ __launch_bounds__(256) void k_prep_x(const float* __restrict__ x,
                                                _Float16* __restrict__ xT,
                                                _Float16* __restrict__ theta) {
    __shared__ _Float16 tile[32 * 136];
    int pb = blockIdx.x;
    int cb = blockIdx.y;
    int n  = blockIdx.z;
    int t  = threadIdx.x;
    int p0 = pb * 128, c0 = cb * 32;

    const float* xbase = x + ((size_t)n * CD + c0) * PD + p0;
#pragma unroll
    for (int i = 0; i < 4; ++i) {
        int idx = i * 256 + t;
        int cl = idx >> 5;
        int ch = idx & 31;
        float4 v = *(const float4*)(xbase + (size_t)cl * PD + ch * 4);
        half4v h;
        h[0] = (_Float16)v.x; h[1] = (_Float16)v.y; h[2] = (_Float16)v.z; h[3] = (_Float16)v.w;
        *(half4v*)&tile[cl * 136 + ch * 4] = h;
    }
    __syncthreads();

    {
        int pl = t >> 1, ch = t & 1;
        _Float16 vals[16] __attribute__((aligned(16)));
#pragma unroll
        for (int j = 0; j < 16; ++j) vals[j] = tile[(ch * 16 + j) * 136 + pl];
        _Float16* dst = xT + ((size_t)n * PD + p0 + pl) * CD + c0 + ch * 16;
        *(uint4*)dst       = *(uint4*)&vals[0];
        *(uint4*)(dst + 8) = *(uint4*)&vals[8];
    }
    {
        int cl = t >> 3, u0 = (t & 7) * 4;
        _Float16 o[4] __attribute__((aligned(8)));
#pragma unroll
        for (int j = 0; j < 4; ++j) {
            int w2 = (u0 + j) * 2;
            float a0 = (float)tile[cl * 136 + w2];
            float a1 = (float)tile[cl * 136 + w2 + 1];
            float a2 = (float)tile[cl * 136 + 64 + w2];
            float a3 = (float)tile[cl * 136 + 64 + w2 + 1];
            o[j] = (_Float16)fmaxf(fmaxf(a0, a1), fmaxf(a2, a3));
        }
        _Float16* dst = theta + ((size_t)n * CD + c0 + cl) * PPD + pb * 32 + u0;
        *(uint2*)dst = *(uint2*)&o[0];
    }
}

// GEMM1: D[a][p] = sum_c Wc[a][c] * x[c][p], 128x128 tile, K=512.
// 2-phase double-buffered global_load_lds pipeline, swizzled LDS.
__global__ __launch_bounds__(256) void k_gemm1(const _Float16* __restrict__ Wc,
                                               const _Float16* __restrict__ xT,
                                               const float* __restrict__ b_g,
                                               const float* __restrict__ b_phi,
                                               _Float16* __restrict__ gT,
                                               _Float16* __restrict__ phi) {
    // staging: 2 bufs x (A 4096 + B 4096) halves = 16384; epilogue reuses as [128][136]=17408
    __shared__ _Float16 smem[17408];

    int pb = blockIdx.x, ab = blockIdx.y, n = blockIdx.z;
    int a0 = ab * 128, p0 = pb * 128;
    int t = threadIdx.x;
    int w = t >> 6, l = t & 63;
    int ln = l & 15, q = l >> 4;
    int mw = (w >> 1) * 64, nw = (w & 1) * 64;

    const f32x4 vzero = {0.f, 0.f, 0.f, 0.f};
    f32x4 acc[4][4];
#pragma unroll
    for (int i = 0; i < 4; ++i)
#pragma unroll
        for (int j = 0; j < 4; ++j) acc[i][j] = vzero;

    const _Float16* Abase = Wc + (size_t)a0 * CD;
    const _Float16* Bbase = xT + ((size_t)n * PD + p0) * CD;

    stage2<CD>(Abase, Bbase, 0, smem, smem + 4096, t);
    __syncthreads();

    for (int ks = 0; ks < 16; ++ks) {
        int oc = (ks & 1) << 13;          // current buffer offset (halves)
        int on = oc ^ 8192;               // next buffer
        if (ks < 15) stage2<CD>(Abase, Bbase, (ks + 1) * 32, smem + on, smem + on + 4096, t);
        _Float16* As = smem + oc;
        _Float16* Bs = smem + oc + 4096;
        half8 af[4], bf[4];
#pragma unroll
        for (int mt = 0; mt < 4; ++mt) af[mt] = *(const half8*)&As[swz_off(mw + mt * 16 + ln, q)];
#pragma unroll
        for (int nt = 0; nt < 4; ++nt) bf[nt] = *(const half8*)&Bs[swz_off(nw + nt * 16 + ln, q)];
#pragma unroll
        for (int mt = 0; mt < 4; ++mt)
#pragma unroll
            for (int nt = 0; nt < 4; ++nt)
                acc[mt][nt] = __builtin_amdgcn_mfma_f32_16x16x32_f16(af[mt], bf[nt], acc[mt][nt], 0, 0, 0);
        __syncthreads();
    }

    bool is_g = (a0 < 256);
    const float* bias = is_g ? b_g : b_phi;
    int abase = a0 - (is_g ? 0 : 256);
    float bv[4][4];
#pragma unroll
    for (int mt = 0; mt < 4; ++mt)
#pragma unroll
        for (int r = 0; r < 4; ++r) bv[mt][r] = bias[abase + mw + mt * 16 + q * 4 + r];

    _Float16* T = smem;   // [row][136]
    if (is_g) {
#pragma unroll
        for (int mt = 0; mt < 4; ++mt)
#pragma unroll
            for (int nt = 0; nt < 4; ++nt)
#pragma unroll
                for (int r = 0; r < 4; ++r) {
                    int al = mw + mt * 16 + q * 4 + r;
                    int pl = nw + nt * 16 + ln;
                    T[pl * 136 + al] = (_Float16)(acc[mt][nt][r] + bv[mt][r]);
                }
        __syncthreads();
#pragma unroll
        for (int i = 0; i < 8; ++i) {
            int idx = i * 256 + t;
            int pl = idx >> 4, ch = idx & 15;
            uint4 v = *(uint4*)&T[pl * 136 + ch * 8];
            *(uint4*)(gT + ((size_t)n * PD + p0 + pl) * AD + a0 + ch * 8) = v;
        }
    } else {
#pragma unroll
        for (int mt = 0; mt < 4; ++mt)
#pragma unroll
            for (int nt = 0; nt < 4; ++nt)
#pragma unroll
                for (int r = 0; r < 4; ++r) {
                    int al = mw + mt * 16 + q * 4 + r;
                    int pl = nw + nt * 16 + ln;
                    T[al * 136 + pl] = (_Float16)(acc[mt][nt][r] + bv[mt][r]);
                }
        __syncthreads();
        int al = t >> 1, hf = t & 1;
        _Float16 o[16] __attribute__((aligned(16)));
#pragma unroll
        for (int j = 0; j < 16; ++j) {
            int u = hf * 16 + j;
            float v0 = (float)T[al * 136 + 2 * u];
            float v1 = (float)T[al * 136 + 2 * u + 1];
            float v2 = (float)T[al * 136 + 64 + 2 * u];
            float v3 = (float)T[al * 136 + 64 + 2 * u + 1];
            o[j] = (_Float16)fmaxf(fmaxf(v0, v1), fmaxf(v2, v3));
        }
        _Float16* dst = phi + ((size_t)n * AD + (a0 - 256) + al) * PPD + pb * 32 + hf * 16;
        *(uint4*)dst       = *(uint4*)&o[0];
        *(uint4*)(dst + 8) = *(uint4*)&o[8];
    }
}

// GEMM2 + softmax, K-split across waves for occupancy.
// Block = (cb: 16 c-rows, n); wave w computes K-slice [w*256, w*256+256) of cmat[16c][256a];
// LDS f32 reduction (pad-65 rows, conflict-free), wave 0 does softmax + store.
__global__ __launch_bounds__(256) void k_gemm2(const _Float16* __restrict__ theta,
                                               const _Float16* __restrict__ phi,
                                               _Float16* __restrict__ attn) {
    __shared__ float red[3 * 64 * 65];    // 49920 B
    int cb = blockIdx.x;   // 0..31
    int n  = blockIdx.y;
    int t = threadIdx.x, w = t >> 6, l = t & 63;
    int ln = l & 15, q = l >> 4;
    int c0 = cb * 16;

    const _Float16* Ab = theta + ((size_t)n * CD + c0 + ln) * PPD + w * 256;
    const _Float16* Bb = phi + ((size_t)n * AD + ln) * PPD + w * 256;

    const f32x4 vzero = {0.f, 0.f, 0.f, 0.f};
    f32x4 acc[16];
#pragma unroll
    for (int i = 0; i < 16; ++i) acc[i] = vzero;

    for (int k0 = 0; k0 < 256; k0 += 32) {
        half8 af = *(const half8*)(Ab + k0 + q * 8);
#pragma unroll
        for (int nt = 0; nt < 16; ++nt) {
            half8 bf = *(const half8*)(Bb + (size_t)nt * 16 * PPD + k0 + q * 8);
            acc[nt] = __builtin_amdgcn_mfma_f32_16x16x32_f16(af, bf, acc[nt], 0, 0, 0);
        }
    }

    if (w > 0) {
        float* dst = red + (w - 1) * 64 * 65 + l * 65;
#pragma unroll
        for (int nt = 0; nt < 16; ++nt)
#pragma unroll
            for (int r = 0; r < 4; ++r) dst[nt * 4 + r] = acc[nt][r];
    }
    __syncthreads();
    if (w == 0) {
#pragma unroll
        for (int j = 0; j < 3; ++j) {
            const float* src = red + j * 64 * 65 + l * 65;
#pragma unroll
            for (int nt = 0; nt < 16; ++nt)
#pragma unroll
                for (int r = 0; r < 4; ++r) acc[nt][r] += src[nt * 4 + r];
        }
        // softmax per D-row (row = q*4+r, cols spread over 16 lanes x 16 tiles)
#pragma unroll
        for (int r = 0; r < 4; ++r) {
            float m = -1e30f;
#pragma unroll
            for (int nt = 0; nt < 16; ++nt) m = fmaxf(m, acc[nt][r]);
#pragma unroll
            for (int s = 1; s < 16; s <<= 1) m = fmaxf(m, __shfl_xor(m, s, 64));
            float sum = 0.f;
#pragma unroll
            for (int nt = 0; nt < 16; ++nt) {
                float e = __expf(acc[nt][r] - m);
                acc[nt][r] = e;
                sum += e;
            }
#pragma unroll
            for (int s = 1; s < 16; s <<= 1) sum += __shfl_xor(sum, s, 64);
            float inv = 1.0f / sum;
            int c = c0 + q * 4 + r;
            _Float16* dst = attn + ((size_t)n * CD + c) * AD + ln;
#pragma unroll
            for (int nt = 0; nt < 16; ++nt) dst[nt * 16] = (_Float16)(acc[nt][r] * inv);
        }
    }
}

// GEMM3: out[c][p] = sum_a attn[c][a] * gT[p][a] + x[c][p].  128x128 tile, K=256.
// Operand-swapped (D[p][c] -> float4 epilogue), 2-phase global_load_lds pipeline.
__global__ __launch_bounds__(256) void k_gemm3(const _Float16* __restrict__ attn,
                                               const _Float16* __restrict__ gT,
                                               const float* __restrict__ x,
                                               float* __restrict__ out) {
    __shared__ _Float16 smem[16384];   // 2 bufs x (As 4096 + Bs 4096)

    int pb = blockIdx.x, cb = blockIdx.y, n = blockIdx.z;
    int c0 = cb * 128, p0 = pb * 128;
    int t = threadIdx.x;
    int w = t >> 6, l = t & 63;
    int ln = l & 15, q = l >> 4;
    int mw = (w >> 1) * 64, nw = (w & 1) * 64;   // mw: p-tile, nw: c-tile

    const f32x4 vzero = {0.f, 0.f, 0.f, 0.f};
    f32x4 acc[4][4];
#pragma unroll
    for (int i = 0; i < 4; ++i)
#pragma unroll
        for (int j = 0; j < 4; ++j) acc[i][j] = vzero;

    const _Float16* Abase = attn + ((size_t)n * CD + c0) * AD;   // 128 c rows
    const _Float16* Bbase = gT + ((size_t)n * PD + p0) * AD;     // 128 p rows

    stage2<AD>(Abase, Bbase, 0, smem, smem + 4096, t);
    __syncthreads();

    for (int ks = 0; ks < 8; ++ks) {
        int oc = (ks & 1) << 13;
        int on = oc ^ 8192;
        if (ks < 7) stage2<AD>(Abase, Bbase, (ks + 1) * 32, smem + on, smem + on + 4096, t);
        _Float16* As = smem + oc;          // attn tile (c rows)
        _Float16* Bs = smem + oc + 4096;   // gT tile (p rows)
        half8 af[4], bf[4];
        // A-operand = gT rows (p) -> D rows = p; B-operand = attn rows (c) -> D cols = c
#pragma unroll
        for (int mt = 0; mt < 4; ++mt) af[mt] = *(const half8*)&Bs[swz_off(mw + mt * 16 + ln, q)];
#pragma unroll
        for (int nt = 0; nt < 4; ++nt) bf[nt] = *(const half8*)&As[swz_off(nw + nt * 16 + ln, q)];
#pragma unroll
        for (int mt = 0; mt < 4; ++mt)
#pragma unroll
            for (int nt = 0; nt < 4; ++nt)
                acc[mt][nt] = __builtin_amdgcn_mfma_f32_16x16x32_f16(af[mt], bf[nt], acc[mt][nt], 0, 0, 0);
        __syncthreads();
    }

    // epilogue: lane (q,ln) of tile (mt,nt) holds p = p0+mw+mt*16+q*4..+3, c = c0+nw+nt*16+ln
#pragma unroll
    for (int mt = 0; mt < 4; ++mt) {
        int p = p0 + mw + mt * 16 + q * 4;
#pragma unroll
        for (int nt = 0; nt < 4; ++nt) {
            int c = c0 + nw + nt * 16 + ln;
            size_t off = ((size_t)n * CD + c) * PD + p;
            f32x4 xv = *(const f32x4*)(x + off);
            *(f32x4*)(out + off) = acc[mt][nt] + xv;
        }
    }
}

extern "C" void kernel_launch(void* const* d_in, const int* in_sizes, int n_in,
                              void* d_out, int out_size, void* d_ws, size_t ws_size,
                              hipStream_t stream) {
    const float* x     = (const float*)d_in[0];
    const float* w_g   = (const float*)d_in[1];
    const float* b_g   = (const float*)d_in[2];
    const float* w_phi = (const float*)d_in[3];
    const float* b_phi = (const float*)d_in[4];
    float* out = (float*)d_out;

    char* ws = (char*)d_ws;
    _Float16* xT    = (_Float16*)(ws + OFF_XT);
    _Float16* Wc    = (_Float16*)(ws + OFF_WC);
    _Float16* theta = (_Float16*)(ws + OFF_THETA);
    _Float16* gT    = (_Float16*)(ws + OFF_GT);
    _Float16* phi   = (_Float16*)(ws + OFF_PHI);
    _Float16* attn  = (_Float16*)(ws + OFF_ATTN);

    k_prep_w<<<dim3(256), 256, 0, stream>>>(w_g, w_phi, Wc);
    k_prep_x<<<dim3(32, 16, 32), 256, 0, stream>>>(x, xT, theta);
    k_gemm1<<<dim3(32, 4, 32), 256, 0, stream>>>(Wc, xT, b_g, b_phi, gT, phi);
    k_gemm2<<<dim3(32, 32), 256, 0, stream>>>(theta, phi, attn);
    k_gemm3<<<dim3(32, 4, 32), 256, 0, stream>>>(attn, gT, x, out);
}